// Round 4
// baseline (146.646 us; speedup 1.0000x reference)
//
#include <hip/hip_runtime.h>
#include <hip/hip_bf16.h>

// LinearPositionInterpolation: out[b, p-1, :] = lerp(value[b, seg, :], value[b, seg+1, :], w)
// seg = searchsorted(index - index[0], p, 'left') - 1, p in [1, m], m = index[n-1]-index[0].
//
// R1: one block per (batch, segment) — no per-thread search, pure streaming stores.
// R3: persistent grid-stride — 2048 blocks, each handles 2 (b,seg) pairs, so the
// second pair's y0/y1 loads overlap the first pair's store drain and block
// dispatch count halves. 134 MB out + ~8 MB in -> ~22 us floor at 6.3 TB/s.

#define DIM 256
#define VEC_PER_ROW (DIM / 4)   // 64 float4 per row == 1 wave per row

typedef float vfloat4 __attribute__((ext_vector_type(4)));

__global__ __launch_bounds__(256) void lpi_kernel(
    const int* __restrict__ index,
    const float* __restrict__ value,
    float* __restrict__ out,
    int n, int m, int npairs)
{
    int nseg = n - 1;
    int lane = threadIdx.x & 63;         // float4 index within the 256-wide row
    int wv   = threadIdx.x >> 6;         // wave id within block (0..3)
    int base = index[0];

    for (int pair = blockIdx.x; pair < npairs; pair += gridDim.x) {
        int seg = pair % nseg;           // wave-uniform
        int b   = pair / nseg;

        int x0  = index[seg]     - base; // tiny, L2-hot after first touch
        int x1  = index[seg + 1] - base;
        int len = x1 - x0;

        const vfloat4* y0 = (const vfloat4*)(value + (size_t)(b * n + seg) * DIM);
        const vfloat4* y1 = y0 + VEC_PER_ROW;  // row seg+1 contiguous

        vfloat4 a = y0[lane];
        vfloat4 c = y1[lane];
        vfloat4 d = c - a;               // diff = y1 - y0, computed once

        float flen = (float)len;

        // rows r = x0 + k  (p = x0 + k + 1), k in [0, len)
        for (int k = wv; k < len; k += 4) {
            float w = (float)(k + 1) / flen;   // == (p - x0)/(x1 - x0)
            vfloat4 o = a + d * w;
            vfloat4* op = (vfloat4*)(out + (size_t)(b * m + x0 + k) * DIM);
            __builtin_nontemporal_store(o, op + lane);
        }
    }
}

extern "C" void kernel_launch(void* const* d_in, const int* in_sizes, int n_in,
                              void* d_out, int out_size, void* d_ws, size_t ws_size,
                              hipStream_t stream) {
    const int*   index = (const int*)d_in[0];
    const float* value = (const float*)d_in[1];
    float*       out   = (float*)d_out;

    int n  = in_sizes[0];                 // 129
    int bd = in_sizes[1] / n;             // batch * dim = 8192
    const int dim = DIM;                  // 256 (per reference setup)
    int batch = bd / dim;                 // 32
    int m = out_size / bd;                // 4096

    int npairs = batch * (n - 1);         // 4096 (b,seg) pairs
    int grid   = npairs / 2;              // 2048 blocks: 2 pairs each (8 blocks/CU)
    if (grid < 1) grid = 1;

    lpi_kernel<<<grid, 256, 0, stream>>>(index, value, out, n, m, npairs);
}